// Round 2
// baseline (6501.662 us; speedup 1.0000x reference)
//
#include <hip/hip_runtime.h>
#include <hip/hip_bf16.h>

#define NUM_CHEM 60000
#define NUM_DIS  40000
#define NN       100000
#define HD       128
#define E1       800000
#define E2       1600000
#define NB       65536

// ---------------------------------------------------------------------------
// K1: in-degree counts (float). Relation-0 edges (e < E1) have disease dsts,
// relation-1 edges have chem dsts -> disjoint, one count array suffices.
__global__ void count_k(const int* __restrict__ dst, float* __restrict__ cnt) {
    int e = blockIdx.x * blockDim.x + threadIdx.x;
    if (e < E2) atomicAdd(&cnt[dst[e]], 1.0f);
}

// ---------------------------------------------------------------------------
// K2: scatter-add raw features by dst. Thread = (edge, 4-feature group).
__global__ void scatter_k(const int* __restrict__ src, const int* __restrict__ dst,
                          const float* __restrict__ x, float* __restrict__ agg) {
    long long t = (long long)blockIdx.x * blockDim.x + threadIdx.x;
    int e = (int)(t >> 5);
    if (e >= E2) return;
    int f = ((int)t & 31) * 4;
    int s = src[e], d = dst[e];
    const float4 v = *reinterpret_cast<const float4*>(x + (size_t)s * HD + f);
    float* o = agg + (size_t)d * HD + f;
    atomicAdd(o + 0, v.x);
    atomicAdd(o + 1, v.y);
    atomicAdd(o + 2, v.z);
    atomicAdd(o + 3, v.w);
}

// ---------------------------------------------------------------------------
// K3: per-node transform: y = x[n] @ Wroot + (agg[n]/max(cnt,1)) @ Wrel[rel(n)]
//     + bias (+ReLU). In-place into agg. Block = 128 threads = one node.
__global__ void transform_k(const float* __restrict__ x, float* __restrict__ agg,
                            const float* __restrict__ cnt,
                            const float* __restrict__ Wroot_l,
                            const float* __restrict__ Wrel_l,
                            const float* __restrict__ bias_l, int do_relu) {
    __shared__ float xs[HD];
    __shared__ float as[HD];
    int n = blockIdx.x;
    int h = threadIdx.x;
    float scale = 1.0f / fmaxf(cnt[n], 1.0f);
    xs[h] = x[(size_t)n * HD + h];
    as[h] = agg[(size_t)n * HD + h] * scale;
    __syncthreads();
    // disease nodes (n >= NUM_CHEM) receive relation 0; chem nodes relation 1
    const float* Wr = Wrel_l + (n < NUM_CHEM ? 1 : 0) * (HD * HD);
    float y = bias_l[h];
#pragma unroll 8
    for (int k = 0; k < HD; ++k) {
        y = fmaf(xs[k], Wroot_l[k * HD + h], y);
        y = fmaf(as[k], Wr[k * HD + h], y);
    }
    if (do_relu) y = fmaxf(y, 0.0f);
    agg[(size_t)n * HD + h] = y;
}

// ---------------------------------------------------------------------------
// K4: scores. Block = 128 threads = one pair. out[b] = sum_h (c@Wscore)[h]*d[h]
__global__ void score_k(const float* __restrict__ xf,
                        const int* __restrict__ chem_ids,
                        const int* __restrict__ dis_ids,
                        const float* __restrict__ Wscore,
                        float* __restrict__ out) {
    __shared__ float cs[HD];
    __shared__ float red[HD];
    int b = blockIdx.x;
    int h = threadIdx.x;
    int cn = chem_ids[b];
    int dn = NUM_CHEM + dis_ids[b];
    cs[h] = xf[(size_t)cn * HD + h];
    float dv = xf[(size_t)dn * HD + h];
    __syncthreads();
    float s = 0.0f;
#pragma unroll 8
    for (int k = 0; k < HD; ++k) s = fmaf(cs[k], Wscore[k * HD + h], s);
    red[h] = s * dv;
    __syncthreads();
    for (int stride = 64; stride > 0; stride >>= 1) {
        if (h < stride) red[h] += red[h + stride];
        __syncthreads();
    }
    if (h == 0) out[b] = red[0];
}

// ---------------------------------------------------------------------------
extern "C" void kernel_launch(void* const* d_in, const int* in_sizes, int n_in,
                              void* d_out, int out_size, void* d_ws, size_t ws_size,
                              hipStream_t stream) {
    const float* node_emb = (const float*)d_in[0];   // (N, H)
    const float* Wrel     = (const float*)d_in[1];   // (L, 2, H, H)
    const float* Wroot    = (const float*)d_in[2];   // (L, H, H)
    const float* bias     = (const float*)d_in[3];   // (L, H)
    const float* Wscore   = (const float*)d_in[4];   // (H, H)
    const int*   src      = (const int*)d_in[5];     // (2E,)
    const int*   dst      = (const int*)d_in[6];     // (2E,)
    const int*   chem_ids = (const int*)d_in[7];     // (B,)
    const int*   dis_ids  = (const int*)d_in[8];     // (B,)
    float* out = (float*)d_out;

    const size_t xbytes = (size_t)NN * HD * sizeof(float);  // 51.2 MB
    char* ws = (char*)d_ws;
    float* xA  = (float*)(ws);
    float* xB  = (float*)(ws + xbytes);
    float* cnt = (float*)(ws + 2 * xbytes);

    // counts (same for both layers)
    hipMemsetAsync(cnt, 0, (size_t)NN * sizeof(float), stream);
    count_k<<<(E2 + 255) / 256, 256, 0, stream>>>(dst, cnt);

    const int scatter_blocks = (int)(((long long)E2 * 32 + 255) / 256);

    // ---- layer 0: x = node_emb, agg -> xA, transform in-place -> xA (ReLU)
    hipMemsetAsync(xA, 0, xbytes, stream);
    scatter_k<<<scatter_blocks, 256, 0, stream>>>(src, dst, node_emb, xA);
    transform_k<<<NN, HD, 0, stream>>>(node_emb, xA, cnt,
                                       Wroot + 0 * HD * HD,
                                       Wrel + 0 * 2 * HD * HD,
                                       bias + 0 * HD, 1);

    // ---- layer 1: x = xA, agg -> xB, transform in-place -> xB (no ReLU)
    hipMemsetAsync(xB, 0, xbytes, stream);
    scatter_k<<<scatter_blocks, 256, 0, stream>>>(src, dst, xA, xB);
    transform_k<<<NN, HD, 0, stream>>>(xA, xB, cnt,
                                       Wroot + 1 * HD * HD,
                                       Wrel + 1 * 2 * HD * HD,
                                       bias + 1 * HD, 0);

    // ---- scoring
    score_k<<<NB, HD, 0, stream>>>(xB, chem_ids, dis_ids, Wscore, out);
}

// Round 3
// 725.758 us; speedup vs baseline: 8.9584x; 8.9584x over previous
//
#include <hip/hip_runtime.h>
#include <hip/hip_bf16.h>

#define NUM_CHEM 60000
#define NUM_DIS  40000
#define NN       100000
#define HD       128
#define E1       800000
#define E2       1600000
#define NB       65536
#define SCAN_B   391   // ceil(NN/256)
#define CBLK     938   // ceil(60000/64)
#define DBLK     625   // 40000/64

// ---------------------------------------------------------------------------
// CSR build: degree count (int atomics), 3-kernel exclusive scan, fill.
__global__ void degcount_k(const int* __restrict__ dst, int* __restrict__ deg) {
    int e = blockIdx.x * blockDim.x + threadIdx.x;
    if (e < E2) atomicAdd(&deg[dst[e]], 1);
}

__global__ void scan1_k(const int* __restrict__ deg, int* __restrict__ row,
                        int* __restrict__ bsum) {
    __shared__ int s[256];
    int tid = threadIdx.x;
    int g = blockIdx.x * 256 + tid;
    int v = (g < NN) ? deg[g] : 0;
    s[tid] = v;
    __syncthreads();
    for (int off = 1; off < 256; off <<= 1) {
        int t = (tid >= off) ? s[tid - off] : 0;
        __syncthreads();
        s[tid] += t;
        __syncthreads();
    }
    if (g < NN) row[g] = s[tid] - v;   // exclusive
    if (tid == 255) bsum[blockIdx.x] = s[255];
}

__global__ void scan2_k(int* __restrict__ bsum) {
    __shared__ int s[512];
    int tid = threadIdx.x;
    int v = (tid < SCAN_B) ? bsum[tid] : 0;
    s[tid] = v;
    __syncthreads();
    for (int off = 1; off < 512; off <<= 1) {
        int t = (tid >= off) ? s[tid - off] : 0;
        __syncthreads();
        s[tid] += t;
        __syncthreads();
    }
    if (tid < SCAN_B) bsum[tid] = s[tid] - v;  // exclusive
}

__global__ void scan3_k(int* __restrict__ row, const int* __restrict__ bsum) {
    int g = blockIdx.x * 256 + threadIdx.x;
    if (g < NN) row[g] += bsum[blockIdx.x];
}

__global__ void fill_k(const int* __restrict__ src, const int* __restrict__ dst,
                       const int* __restrict__ row, int* __restrict__ cursor,
                       int* __restrict__ csr) {
    int e = blockIdx.x * blockDim.x + threadIdx.x;
    if (e >= E2) return;
    int d = dst[e];
    int p = atomicAdd(&cursor[d], 1);
    csr[row[d] + p] = src[e];
}

// ---------------------------------------------------------------------------
// Gather-mean: half-wave (32 lanes x float4) per node, coalesced 512B row reads.
__global__ void gather_k(const int* __restrict__ csr, const int* __restrict__ row,
                         const int* __restrict__ deg, const float* __restrict__ x,
                         float* __restrict__ agg) {
    int t = blockIdx.x * 256 + threadIdx.x;
    int n = t >> 5;
    if (n >= NN) return;
    int f = t & 31;
    const float4* x4 = (const float4*)x;
    int base = row[n], d = deg[n];
    float ax = 0.f, ay = 0.f, az = 0.f, aw = 0.f;
    int j = 0;
    for (; j + 1 < d; j += 2) {
        int s0 = csr[base + j], s1 = csr[base + j + 1];
        float4 a = x4[(size_t)s0 * 32 + f];
        float4 b = x4[(size_t)s1 * 32 + f];
        ax += a.x + b.x; ay += a.y + b.y; az += a.z + b.z; aw += a.w + b.w;
    }
    if (j < d) {
        int s0 = csr[base + j];
        float4 a = x4[(size_t)s0 * 32 + f];
        ax += a.x; ay += a.y; az += a.z; aw += a.w;
    }
    float sc = 1.0f / fmaxf((float)d, 1.0f);
    float4 o; o.x = ax * sc; o.y = ay * sc; o.z = az * sc; o.w = aw * sc;
    ((float4*)agg)[(size_t)n * 32 + f] = o;
}

// ---------------------------------------------------------------------------
// Register-blocked f32 GEMM transform. 64-node tile, 256 threads,
// thread = 8 nodes x 4 features. In-place: agg tile staged in LDS, then
// y = x@Wroot + agg@Wr + bias (+relu) overwrites agg rows of OWN tile only.
__global__ __launch_bounds__(256, 2)
void transform_k(const float* __restrict__ x, float* __restrict__ agg,
                 const float* __restrict__ Wroot_l, const float* __restrict__ Wrel_l,
                 const float* __restrict__ bias_l, int do_relu) {
    __shared__ float xs[64][HD];
    __shared__ float as[64][HD];
    int b = blockIdx.x;
    int base, limit;
    const float* Wr;
    if (b < CBLK) { base = b * 64; limit = NUM_CHEM; Wr = Wrel_l + HD * HD; }   // chem: rel 1
    else          { base = NUM_CHEM + (b - CBLK) * 64; limit = NN; Wr = Wrel_l; } // dis: rel 0
    int tid = threadIdx.x;
    const float4* x4 = (const float4*)x;
    const float4* a4 = (const float4*)agg;
#pragma unroll
    for (int i = 0; i < 8; ++i) {
        int id = tid + i * 256;        // 0..2047 float4 slots
        int r = id >> 5, c = id & 31;
        int ng = base + r;
        float4 vx, va;
        if (ng < limit) { vx = x4[(size_t)ng * 32 + c]; va = a4[(size_t)ng * 32 + c]; }
        else { vx = make_float4(0, 0, 0, 0); va = vx; }
        *(float4*)&xs[r][c * 4] = vx;
        *(float4*)&as[r][c * 4] = va;
    }
    __syncthreads();
    int tx = tid & 31, ty = tid >> 5;
    int nb = ty * 8;
    float4 acc[8];
#pragma unroll
    for (int n = 0; n < 8; ++n) acc[n] = make_float4(0, 0, 0, 0);
    const float4* WR4 = (const float4*)Wroot_l;
    const float4* WA4 = (const float4*)Wr;
    for (int k4 = 0; k4 < HD; k4 += 4) {
        float4 wr[4], wa[4];
#pragma unroll
        for (int j = 0; j < 4; ++j) {
            wr[j] = WR4[(k4 + j) * 32 + tx];
            wa[j] = WA4[(k4 + j) * 32 + tx];
        }
#pragma unroll
        for (int n = 0; n < 8; ++n) {
            float4 xv = *(const float4*)&xs[nb + n][k4];
            float4 av = *(const float4*)&as[nb + n][k4];
            acc[n].x += xv.x * wr[0].x + xv.y * wr[1].x + xv.z * wr[2].x + xv.w * wr[3].x
                      + av.x * wa[0].x + av.y * wa[1].x + av.z * wa[2].x + av.w * wa[3].x;
            acc[n].y += xv.x * wr[0].y + xv.y * wr[1].y + xv.z * wr[2].y + xv.w * wr[3].y
                      + av.x * wa[0].y + av.y * wa[1].y + av.z * wa[2].y + av.w * wa[3].y;
            acc[n].z += xv.x * wr[0].z + xv.y * wr[1].z + xv.z * wr[2].z + xv.w * wr[3].z
                      + av.x * wa[0].z + av.y * wa[1].z + av.z * wa[2].z + av.w * wa[3].z;
            acc[n].w += xv.x * wr[0].w + xv.y * wr[1].w + xv.z * wr[2].w + xv.w * wr[3].w
                      + av.x * wa[0].w + av.y * wa[1].w + av.z * wa[2].w + av.w * wa[3].w;
        }
    }
    float4 bias4 = *(const float4*)&bias_l[tx * 4];
#pragma unroll
    for (int n = 0; n < 8; ++n) {
        int ng = base + nb + n;
        if (ng < limit) {
            float4 y;
            y.x = acc[n].x + bias4.x; y.y = acc[n].y + bias4.y;
            y.z = acc[n].z + bias4.z; y.w = acc[n].w + bias4.w;
            if (do_relu) {
                y.x = fmaxf(y.x, 0.f); y.y = fmaxf(y.y, 0.f);
                y.z = fmaxf(y.z, 0.f); y.w = fmaxf(y.w, 0.f);
            }
            ((float4*)agg)[(size_t)ng * 32 + tx] = y;
        }
    }
}

// ---------------------------------------------------------------------------
// zc' = x[0:60000] @ Wscore  (same tiling, single operand)
__global__ __launch_bounds__(256, 2)
void scoregemm_k(const float* __restrict__ x, const float* __restrict__ Wscore,
                 float* __restrict__ zcp) {
    __shared__ float xs[64][HD];
    int base = blockIdx.x * 64;
    int tid = threadIdx.x;
    const float4* x4 = (const float4*)x;
#pragma unroll
    for (int i = 0; i < 8; ++i) {
        int id = tid + i * 256;
        int r = id >> 5, c = id & 31;
        int ng = base + r;
        float4 vx = (ng < NUM_CHEM) ? x4[(size_t)ng * 32 + c] : make_float4(0, 0, 0, 0);
        *(float4*)&xs[r][c * 4] = vx;
    }
    __syncthreads();
    int tx = tid & 31, ty = tid >> 5;
    int nb = ty * 8;
    float4 acc[8];
#pragma unroll
    for (int n = 0; n < 8; ++n) acc[n] = make_float4(0, 0, 0, 0);
    const float4* W4 = (const float4*)Wscore;
    for (int k4 = 0; k4 < HD; k4 += 4) {
        float4 w[4];
#pragma unroll
        for (int j = 0; j < 4; ++j) w[j] = W4[(k4 + j) * 32 + tx];
#pragma unroll
        for (int n = 0; n < 8; ++n) {
            float4 xv = *(const float4*)&xs[nb + n][k4];
            acc[n].x += xv.x * w[0].x + xv.y * w[1].x + xv.z * w[2].x + xv.w * w[3].x;
            acc[n].y += xv.x * w[0].y + xv.y * w[1].y + xv.z * w[2].y + xv.w * w[3].y;
            acc[n].z += xv.x * w[0].z + xv.y * w[1].z + xv.z * w[2].z + xv.w * w[3].z;
            acc[n].w += xv.x * w[0].w + xv.y * w[1].w + xv.z * w[2].w + xv.w * w[3].w;
        }
    }
#pragma unroll
    for (int n = 0; n < 8; ++n) {
        int ng = base + nb + n;
        if (ng < NUM_CHEM) ((float4*)zcp)[(size_t)ng * 32 + tx] = acc[n];
    }
}

// ---------------------------------------------------------------------------
// out[p] = dot(zc'[chem_ids[p]], x_final[NUM_CHEM + dis_ids[p]])
__global__ void dot_k(const float* __restrict__ zcp, const float* __restrict__ xfin,
                      const int* __restrict__ chem_ids, const int* __restrict__ dis_ids,
                      float* __restrict__ out) {
    int t = blockIdx.x * 256 + threadIdx.x;
    int p = t >> 5;
    if (p >= NB) return;
    int f = t & 31;
    int c = chem_ids[p];
    int dn = NUM_CHEM + dis_ids[p];
    float4 a = ((const float4*)zcp)[(size_t)c * 32 + f];
    float4 b = ((const float4*)xfin)[(size_t)dn * 32 + f];
    float s = a.x * b.x + a.y * b.y + a.z * b.z + a.w * b.w;
#pragma unroll
    for (int m = 16; m >= 1; m >>= 1) s += __shfl_xor(s, m);
    if (f == 0) out[p] = s;
}

// ---------------------------------------------------------------------------
extern "C" void kernel_launch(void* const* d_in, const int* in_sizes, int n_in,
                              void* d_out, int out_size, void* d_ws, size_t ws_size,
                              hipStream_t stream) {
    const float* node_emb = (const float*)d_in[0];
    const float* Wrel     = (const float*)d_in[1];   // (L, 2, H, H)
    const float* Wroot    = (const float*)d_in[2];   // (L, H, H)
    const float* bias     = (const float*)d_in[3];   // (L, H)
    const float* Wscore   = (const float*)d_in[4];   // (H, H)
    const int*   src      = (const int*)d_in[5];
    const int*   dst      = (const int*)d_in[6];
    const int*   chem_ids = (const int*)d_in[7];
    const int*   dis_ids  = (const int*)d_in[8];
    float* out = (float*)d_out;

    const size_t xbytes = (size_t)NN * HD * sizeof(float);  // 51.2 MB
    char* ws = (char*)d_ws;
    float* xA    = (float*)(ws);
    float* xB    = (float*)(ws + xbytes);
    int*   deg   = (int*)(ws + 2 * xbytes);
    int*   row   = (int*)(ws + 2 * xbytes + 400000);
    int*   cursor= (int*)(ws + 2 * xbytes + 800000);
    int*   bsum  = (int*)(ws + 2 * xbytes + 1200000);
    int*   csr   = (int*)(ws + 2 * xbytes + 1204096);

    // ---- CSR build (reused by both layers)
    hipMemsetAsync(deg, 0, NN * sizeof(int), stream);
    hipMemsetAsync(cursor, 0, NN * sizeof(int), stream);
    degcount_k<<<(E2 + 255) / 256, 256, 0, stream>>>(dst, deg);
    scan1_k<<<SCAN_B, 256, 0, stream>>>(deg, row, bsum);
    scan2_k<<<1, 512, 0, stream>>>(bsum);
    scan3_k<<<SCAN_B, 256, 0, stream>>>(row, bsum);
    fill_k<<<(E2 + 255) / 256, 256, 0, stream>>>(src, dst, row, cursor, csr);

    // ---- layer 0: agg(mean) -> xA, transform in-place (ReLU)
    gather_k<<<12500, 256, 0, stream>>>(csr, row, deg, node_emb, xA);
    transform_k<<<CBLK + DBLK, 256, 0, stream>>>(node_emb, xA,
                                                 Wroot, Wrel, bias, 1);

    // ---- layer 1: agg(mean) -> xB, transform in-place (no ReLU)
    gather_k<<<12500, 256, 0, stream>>>(csr, row, deg, xA, xB);
    transform_k<<<CBLK + DBLK, 256, 0, stream>>>(xA, xB,
                                                 Wroot + HD * HD, Wrel + 2 * HD * HD,
                                                 bias + HD, 0);

    // ---- scoring: zc' = xB[:60000] @ Wscore -> xA (free), then pair dots
    scoregemm_k<<<CBLK, 256, 0, stream>>>(xB, Wscore, xA);
    dot_k<<<NB * 32 / 256, 256, 0, stream>>>(xA, xB, chem_ids, dis_ids, out);
}

// Round 8
// 516.448 us; speedup vs baseline: 12.5892x; 1.4053x over previous
//
#include <hip/hip_runtime.h>
#include <hip/hip_bf16.h>

#define NUM_CHEM 60000
#define NUM_DIS  40000
#define NN       100000
#define HD       128
#define E1       800000
#define E2       1600000
#define NB       65536
#define SCAN_B   391   // ceil(NN/256)
#define CHEM_TB  469   // ceil(60000/128)
#define DIS_TB   313   // ceil(40000/128)

typedef __attribute__((ext_vector_type(8))) short short8;
typedef __attribute__((ext_vector_type(4))) float f32x4;

__device__ __forceinline__ unsigned short f2bf(float f) {
    unsigned u = __builtin_bit_cast(unsigned, f);
    u = (u + 0x7fffu + ((u >> 16) & 1u)) >> 16;
    return (unsigned short)u;
}
__device__ __forceinline__ float bf2f(short h) {
    unsigned u = ((unsigned)(unsigned short)h) << 16;
    return __builtin_bit_cast(float, u);
}
__device__ __forceinline__ short8 ldfrag(const short* p) {
    return *reinterpret_cast<const short8*>(p);
}

// ---------------------------------------------------------------------------
// CSR build (unchanged): degree, 3-kernel scan, fill.
__global__ void degcount_k(const int* __restrict__ dst, int* __restrict__ deg) {
    int e = blockIdx.x * blockDim.x + threadIdx.x;
    if (e < E2) atomicAdd(&deg[dst[e]], 1);
}

__global__ void scan1_k(const int* __restrict__ deg, int* __restrict__ row,
                        int* __restrict__ bsum) {
    __shared__ int s[256];
    int tid = threadIdx.x;
    int g = blockIdx.x * 256 + tid;
    int v = (g < NN) ? deg[g] : 0;
    s[tid] = v;
    __syncthreads();
    for (int off = 1; off < 256; off <<= 1) {
        int t = (tid >= off) ? s[tid - off] : 0;
        __syncthreads();
        s[tid] += t;
        __syncthreads();
    }
    if (g < NN) row[g] = s[tid] - v;
    if (tid == 255) bsum[blockIdx.x] = s[255];
}

__global__ void scan2_k(int* __restrict__ bsum) {
    __shared__ int s[512];
    int tid = threadIdx.x;
    int v = (tid < SCAN_B) ? bsum[tid] : 0;
    s[tid] = v;
    __syncthreads();
    for (int off = 1; off < 512; off <<= 1) {
        int t = (tid >= off) ? s[tid - off] : 0;
        __syncthreads();
        s[tid] += t;
        __syncthreads();
    }
    if (tid < SCAN_B) bsum[tid] = s[tid] - v;
}

__global__ void scan3_k(int* __restrict__ row, const int* __restrict__ bsum) {
    int g = blockIdx.x * 256 + threadIdx.x;
    if (g < NN) row[g] += bsum[blockIdx.x];
}

__global__ void fill_k(const int* __restrict__ src, const int* __restrict__ dst,
                       const int* __restrict__ row, int* __restrict__ cursor,
                       int* __restrict__ csr) {
    int e = blockIdx.x * blockDim.x + threadIdx.x;
    if (e >= E2) return;
    int d = dst[e];
    int p = atomicAdd(&cursor[d], 1);
    csr[row[d] + p] = src[e];
}

// ---------------------------------------------------------------------------
// node_emb f32 -> bf16 (8 elems/thread)
__global__ void cvt_k(const float* __restrict__ src, short* __restrict__ dst) {
    int i = blockIdx.x * 256 + threadIdx.x;           // 8-elem group
    if (i >= NN * HD / 8) return;
    const float4* s4 = (const float4*)src;
    float4 a = s4[2 * i], b = s4[2 * i + 1];
    short8 o;
    o[0] = (short)f2bf(a.x); o[1] = (short)f2bf(a.y);
    o[2] = (short)f2bf(a.z); o[3] = (short)f2bf(a.w);
    o[4] = (short)f2bf(b.x); o[5] = (short)f2bf(b.y);
    o[6] = (short)f2bf(b.z); o[7] = (short)f2bf(b.w);
    ((short8*)dst)[i] = o;
}

// Transpose+convert 7 weight matrices to bf16 W^T[n][k].
// 0:Wroot0 1:Wrel00 2:Wrel01 3:Wroot1 4:Wrel10 5:Wrel11 6:Wscore
__global__ void wprep_k(const float* __restrict__ Wrel, const float* __restrict__ Wroot,
                        const float* __restrict__ Wscore, short* __restrict__ WT) {
    int m = blockIdx.x;
    const float* src;
    switch (m) {
        case 0: src = Wroot; break;
        case 1: src = Wrel; break;
        case 2: src = Wrel + 16384; break;
        case 3: src = Wroot + 16384; break;
        case 4: src = Wrel + 2 * 16384; break;
        case 5: src = Wrel + 3 * 16384; break;
        default: src = Wscore; break;
    }
    short* dstm = WT + m * 16384;
    for (int i = threadIdx.x; i < 16384; i += 256) {
        int k = i >> 7, n = i & 127;
        dstm[n * 128 + k] = (short)f2bf(src[i]);
    }
}

// ---------------------------------------------------------------------------
// Gather-mean (bf16 in, bf16 out, f32 accum). 16 lanes x short8 per node.
__global__ void gather_k(const int* __restrict__ csr, const int* __restrict__ rowp,
                         const int* __restrict__ deg, const short* __restrict__ x,
                         short* __restrict__ agg) {
    int t = blockIdx.x * 256 + threadIdx.x;
    int n = t >> 4;
    if (n >= NN) return;
    int f = (t & 15) * 8;
    int base = rowp[n], d = deg[n];
    float a[8];
#pragma unroll
    for (int i = 0; i < 8; ++i) a[i] = 0.f;
    int j = 0;
    for (; j + 1 < d; j += 2) {
        int s0 = csr[base + j], s1 = csr[base + j + 1];
        short8 u = ldfrag(x + (size_t)s0 * HD + f);
        short8 v = ldfrag(x + (size_t)s1 * HD + f);
#pragma unroll
        for (int i = 0; i < 8; ++i) a[i] += bf2f(u[i]) + bf2f(v[i]);
    }
    if (j < d) {
        int s0 = csr[base + j];
        short8 u = ldfrag(x + (size_t)s0 * HD + f);
#pragma unroll
        for (int i = 0; i < 8; ++i) a[i] += bf2f(u[i]);
    }
    float sc = 1.0f / fmaxf((float)d, 1.0f);
    short8 o;
#pragma unroll
    for (int i = 0; i < 8; ++i) o[i] = (short)f2bf(a[i] * sc);
    *(short8*)(agg + (size_t)n * HD + f) = o;
}

// ---------------------------------------------------------------------------
// MFMA transform: y = x@Wroot + agg@Wrel[rel] + bias (+relu), in-place to agg.
// 128-node block, 4 waves, wave = 32 rows x 128 cols, mfma 16x16x32 bf16.
__global__ __launch_bounds__(256)
void transform_k(const short* __restrict__ x, short* __restrict__ agg,
                 const short* __restrict__ WrootT, const short* __restrict__ WrelT,
                 const float* __restrict__ bias_l, int do_relu) {
    int b = blockIdx.x;
    int base, limit;
    const short* WrT;
    if (b < CHEM_TB) { base = b * 128; limit = NUM_CHEM; WrT = WrelT + 16384; }  // rel 1
    else { base = NUM_CHEM + (b - CHEM_TB) * 128; limit = NN; WrT = WrelT; }     // rel 0
    int lane = threadIdx.x & 63, w = threadIdx.x >> 6;
    int l15 = lane & 15, lg = lane >> 4;
    int rb = base + w * 32;
    int m0 = rb + l15, m1 = m0 + 16;
    bool v0 = m0 < limit, v1 = m1 < limit;
    f32x4 acc[2][8];
#pragma unroll
    for (int mt = 0; mt < 2; ++mt)
#pragma unroll
        for (int nt = 0; nt < 8; ++nt) acc[mt][nt] = (f32x4){0.f, 0.f, 0.f, 0.f};
    const short8 zero8 = (short8){0, 0, 0, 0, 0, 0, 0, 0};
#pragma unroll
    for (int ks = 0; ks < 4; ++ks) {
        int ko = ks * 32 + lg * 8;
        short8 ax0 = v0 ? ldfrag(x + (size_t)m0 * HD + ko) : zero8;
        short8 ax1 = v1 ? ldfrag(x + (size_t)m1 * HD + ko) : zero8;
        short8 ag0 = v0 ? ldfrag(agg + (size_t)m0 * HD + ko) : zero8;
        short8 ag1 = v1 ? ldfrag(agg + (size_t)m1 * HD + ko) : zero8;
#pragma unroll
        for (int nt = 0; nt < 8; ++nt) {
            short8 br = ldfrag(WrootT + (nt * 16 + l15) * HD + ko);
            short8 bg = ldfrag(WrT + (nt * 16 + l15) * HD + ko);
            acc[0][nt] = __builtin_amdgcn_mfma_f32_16x16x32_bf16(ax0, br, acc[0][nt], 0, 0, 0);
            acc[1][nt] = __builtin_amdgcn_mfma_f32_16x16x32_bf16(ax1, br, acc[1][nt], 0, 0, 0);
            acc[0][nt] = __builtin_amdgcn_mfma_f32_16x16x32_bf16(ag0, bg, acc[0][nt], 0, 0, 0);
            acc[1][nt] = __builtin_amdgcn_mfma_f32_16x16x32_bf16(ag1, bg, acc[1][nt], 0, 0, 0);
        }
    }
#pragma unroll
    for (int mt = 0; mt < 2; ++mt) {
#pragma unroll
        for (int r = 0; r < 4; ++r) {
            int row = rb + mt * 16 + lg * 4 + r;
            if (row < limit) {
#pragma unroll
                for (int nt = 0; nt < 8; ++nt) {
                    int col = nt * 16 + l15;
                    float v = acc[mt][nt][r] + bias_l[col];
                    if (do_relu) v = fmaxf(v, 0.f);
                    agg[(size_t)row * HD + col] = (short)f2bf(v);
                }
            }
        }
    }
}

// ---------------------------------------------------------------------------
// zc' = x[0:60000] @ Wscore (bf16 MFMA, same geometry, separate output)
__global__ __launch_bounds__(256)
void scoregemm_k(const short* __restrict__ x, const short* __restrict__ WT,
                 short* __restrict__ zcp) {
    int base = blockIdx.x * 128;
    int lane = threadIdx.x & 63, w = threadIdx.x >> 6;
    int l15 = lane & 15, lg = lane >> 4;
    int rb = base + w * 32;
    int m0 = rb + l15, m1 = m0 + 16;
    bool v0 = m0 < NUM_CHEM, v1 = m1 < NUM_CHEM;
    f32x4 acc[2][8];
#pragma unroll
    for (int mt = 0; mt < 2; ++mt)
#pragma unroll
        for (int nt = 0; nt < 8; ++nt) acc[mt][nt] = (f32x4){0.f, 0.f, 0.f, 0.f};
    const short8 zero8 = (short8){0, 0, 0, 0, 0, 0, 0, 0};
#pragma unroll
    for (int ks = 0; ks < 4; ++ks) {
        int ko = ks * 32 + lg * 8;
        short8 a0 = v0 ? ldfrag(x + (size_t)m0 * HD + ko) : zero8;
        short8 a1 = v1 ? ldfrag(x + (size_t)m1 * HD + ko) : zero8;
#pragma unroll
        for (int nt = 0; nt < 8; ++nt) {
            short8 bw = ldfrag(WT + (nt * 16 + l15) * HD + ko);
            acc[0][nt] = __builtin_amdgcn_mfma_f32_16x16x32_bf16(a0, bw, acc[0][nt], 0, 0, 0);
            acc[1][nt] = __builtin_amdgcn_mfma_f32_16x16x32_bf16(a1, bw, acc[1][nt], 0, 0, 0);
        }
    }
#pragma unroll
    for (int mt = 0; mt < 2; ++mt) {
#pragma unroll
        for (int r = 0; r < 4; ++r) {
            int row = rb + mt * 16 + lg * 4 + r;
            if (row < NUM_CHEM) {
#pragma unroll
                for (int nt = 0; nt < 8; ++nt) {
                    int col = nt * 16 + l15;
                    zcp[(size_t)row * HD + col] = (short)f2bf(acc[mt][nt][r]);
                }
            }
        }
    }
}

// ---------------------------------------------------------------------------
// out[p] = dot(zc'[chem_ids[p]], xfin[NUM_CHEM + dis_ids[p]])   (16 lanes/pair)
__global__ void dot_k(const short* __restrict__ zcp, const short* __restrict__ xfin,
                      const int* __restrict__ chem_ids, const int* __restrict__ dis_ids,
                      float* __restrict__ out) {
    int t = blockIdx.x * 256 + threadIdx.x;
    int p = t >> 4;
    if (p >= NB) return;
    int f = (t & 15) * 8;
    int c = chem_ids[p];
    int dn = NUM_CHEM + dis_ids[p];
    short8 a = ldfrag(zcp + (size_t)c * HD + f);
    short8 b = ldfrag(xfin + (size_t)dn * HD + f);
    float s = 0.f;
#pragma unroll
    for (int i = 0; i < 8; ++i) s += bf2f(a[i]) * bf2f(b[i]);
    s += __shfl_xor(s, 1);
    s += __shfl_xor(s, 2);
    s += __shfl_xor(s, 4);
    s += __shfl_xor(s, 8);
    if ((t & 15) == 0) out[p] = s;
}

// ---------------------------------------------------------------------------
extern "C" void kernel_launch(void* const* d_in, const int* in_sizes, int n_in,
                              void* d_out, int out_size, void* d_ws, size_t ws_size,
                              hipStream_t stream) {
    const float* node_emb = (const float*)d_in[0];
    const float* Wrel     = (const float*)d_in[1];
    const float* Wroot    = (const float*)d_in[2];
    const float* bias     = (const float*)d_in[3];
    const float* Wscore   = (const float*)d_in[4];
    const int*   src      = (const int*)d_in[5];
    const int*   dst      = (const int*)d_in[6];
    const int*   chem_ids = (const int*)d_in[7];
    const int*   dis_ids  = (const int*)d_in[8];
    float* out = (float*)d_out;

    const size_t XB = (size_t)NN * HD * 2;          // 25.6 MB bf16 feature buf
    const size_t ZB = (size_t)NUM_CHEM * HD * 2;    // 15.36 MB
    char* ws = (char*)d_ws;
    short* P    = (short*)(ws);                     // x0 / g1 / x2
    short* Q    = (short*)(ws + XB);                // g0 / x1
    short* R    = (short*)(ws + 2 * XB);            // zc'
    short* WT   = (short*)(ws + 2 * XB + ZB);       // 7 x 128x128 bf16 W^T
    char*  ip   = ws + 2 * XB + ZB + 7 * 16384 * 2;
    int* deg    = (int*)(ip);
    int* rowp   = (int*)(ip + 400000);
    int* cursor = (int*)(ip + 800000);
    int* bsum   = (int*)(ip + 1200000);
    int* csr    = (int*)(ip + 1204096);

    // ---- CSR build
    hipMemsetAsync(deg, 0, NN * sizeof(int), stream);
    hipMemsetAsync(cursor, 0, NN * sizeof(int), stream);
    degcount_k<<<(E2 + 255) / 256, 256, 0, stream>>>(dst, deg);
    scan1_k<<<SCAN_B, 256, 0, stream>>>(deg, rowp, bsum);
    scan2_k<<<1, 512, 0, stream>>>(bsum);
    scan3_k<<<SCAN_B, 256, 0, stream>>>(rowp, bsum);
    fill_k<<<(E2 + 255) / 256, 256, 0, stream>>>(src, dst, rowp, cursor, csr);

    // ---- precision prep
    cvt_k<<<(NN * HD / 8 + 255) / 256, 256, 0, stream>>>(node_emb, P);
    wprep_k<<<7, 256, 0, stream>>>(Wrel, Wroot, Wscore, WT);

    // ---- layer 0
    gather_k<<<(NN * 16 + 255) / 256, 256, 0, stream>>>(csr, rowp, deg, P, Q);
    transform_k<<<CHEM_TB + DIS_TB, 256, 0, stream>>>(P, Q, WT, WT + 16384, bias, 1);

    // ---- layer 1
    gather_k<<<(NN * 16 + 255) / 256, 256, 0, stream>>>(csr, rowp, deg, Q, P);
    transform_k<<<CHEM_TB + DIS_TB, 256, 0, stream>>>(Q, P, WT + 3 * 16384,
                                                      WT + 4 * 16384, bias + HD, 0);

    // ---- scoring
    scoregemm_k<<<CHEM_TB, 256, 0, stream>>>(P, WT + 6 * 16384, R);
    dot_k<<<NB * 16 / 256, 256, 0, stream>>>(R, P, chem_ids, dis_ids, out);
}